// Round 6
// baseline (2034.649 us; speedup 1.0000x reference)
//
#include <hip/hip_runtime.h>
#include <hip/hip_fp16.h>

#define NN 100000
#define NE 1600000
#define NPAD 100352          // NN rounded up to 256
#define ACCS 65              // LDS accumulator row stride (bank-conflict pad)

// ---------------- CSR build ----------------

__global__ void k_deg_count(const int* __restrict__ dst, int* __restrict__ deg, int e) {
    int i = blockIdx.x * blockDim.x + threadIdx.x;
    if (i < e) atomicAdd(&deg[dst[i]], 1);
}

__global__ __launch_bounds__(256) void k_part(const int* __restrict__ deg,
                                              int* __restrict__ bsum, int n) {
    __shared__ int sp[256];
    int i = blockIdx.x * 256 + threadIdx.x;
    sp[threadIdx.x] = (i < n) ? deg[i] : 0;
    __syncthreads();
    for (int off = 128; off > 0; off >>= 1) {
        if (threadIdx.x < off) sp[threadIdx.x] += sp[threadIdx.x + off];
        __syncthreads();
    }
    if (threadIdx.x == 0) bsum[blockIdx.x] = sp[0];
}

__global__ __launch_bounds__(512) void k_top(const int* __restrict__ bsum,
                                             int* __restrict__ boff, int nb,
                                             int* __restrict__ rowptr, int n, int e) {
    __shared__ int sp[512];
    int t = threadIdx.x;
    int v = (t < nb) ? bsum[t] : 0;
    sp[t] = v;
    __syncthreads();
    for (int off = 1; off < 512; off <<= 1) {
        int u = (t >= off) ? sp[t - off] : 0;
        __syncthreads();
        sp[t] += u;
        __syncthreads();
    }
    if (t < nb) boff[t] = sp[t] - v;
    if (t == 0) rowptr[n] = e;
}

__global__ __launch_bounds__(256) void k_write(const int* __restrict__ deg,
                                               const int* __restrict__ boff,
                                               int* __restrict__ rowptr,
                                               float* __restrict__ dinv, int n) {
    __shared__ int sp[256];
    int t = threadIdx.x;
    int i = blockIdx.x * 256 + t;
    int d = (i < n) ? deg[i] : 0;
    sp[t] = d;
    __syncthreads();
    for (int off = 1; off < 256; off <<= 1) {
        int u = (t >= off) ? sp[t - off] : 0;
        __syncthreads();
        sp[t] += u;
        __syncthreads();
    }
    if (i < n) {
        rowptr[i] = boff[blockIdx.x] + sp[t] - d;   // exclusive
        dinv[i] = rsqrtf((float)(d + 1));           // +1 = self-loop
    }
}

// dst-range-filtered fill: pass p handles d in [lo, hi) so csr writes stay
// inside a ~1.6 MB region that the L2s can hold (kills write-thrash).
// Entry packs src (17 bits) | block-local dst (6 bits) << 17.
__global__ void k_fill(const int* __restrict__ src, const int* __restrict__ dst,
                       const int* __restrict__ rowptr, int* __restrict__ cursor,
                       unsigned* __restrict__ csr, int e, int lo, int hi) {
    int i = blockIdx.x * blockDim.x + threadIdx.x;
    if (i < e) {
        int d = dst[i];
        if (d >= lo && d < hi) {
            int idx = rowptr[d] + atomicAdd(&cursor[d], 1);
            csr[idx] = (unsigned)src[i] | ((unsigned)(d & 63) << 17);
        }
    }
}

// ---------------- layer-1 GEMM: g1 = fp16( dinv .* (x @ W1) ) ----------------

__global__ __launch_bounds__(256) void k_gemm1(const float* __restrict__ A,
                                               const float* __restrict__ W,
                                               const float* __restrict__ dinv,
                                               __half* __restrict__ out, int n) {
    __shared__ float sX[32 * 64];
    __shared__ float sW[64 * 64];
    int row0 = blockIdx.x * 32;
    for (int i = threadIdx.x; i < 16 * 64; i += 256)
        ((float4*)sW)[i] = ((const float4*)W)[i];
    for (int i = threadIdx.x; i < 32 * 16; i += 256) {
        int r = i >> 4, c4 = i & 15;
        int row = row0 + r;
        float4 v = (row < n) ? ((const float4*)(A + ((size_t)row << 6)))[c4]
                             : make_float4(0.f, 0.f, 0.f, 0.f);
        ((float4*)sX)[i] = v;
    }
    __syncthreads();

    int ci = (threadIdx.x & 15) * 4;
    int r0 = (threadIdx.x >> 4) * 2;
    float acc[2][4] = {};
#pragma unroll
    for (int k = 0; k < 64; ++k) {
        float a0 = sX[(r0 << 6) + k];
        float a1 = sX[((r0 + 1) << 6) + k];
        float4 w = *(const float4*)&sW[(k << 6) + ci];
        acc[0][0] += a0 * w.x; acc[0][1] += a0 * w.y;
        acc[0][2] += a0 * w.z; acc[0][3] += a0 * w.w;
        acc[1][0] += a1 * w.x; acc[1][1] += a1 * w.y;
        acc[1][2] += a1 * w.z; acc[1][3] += a1 * w.w;
    }
#pragma unroll
    for (int rr = 0; rr < 2; ++rr) {
        int row = row0 + r0 + rr;
        if (row < n) {
            float di = dinv[row];
            union { uint2 u; __half2 h[2]; } P;
            P.h[0] = __float22half2_rn(make_float2(acc[rr][0] * di, acc[rr][1] * di));
            P.h[1] = __float22half2_rn(make_float2(acc[rr][2] * di, acc[rr][3] * di));
            *(uint2*)(out + ((size_t)row << 6) + ci) = P.u;
        }
    }
}

// ---------------- edge-parallel aggregate: 64 nodes/block, LDS accumulators ----
// t[d] = sum_{j in N(d)} g[s_j] + g[d]       (g = dinv .* h)
// MODE 1: gout = fp16( relu(dinv*t + bias) * dinv )
// MODE 2: h = relu(dinv*t + bias); gout = fp16( (h @ Wn) * dinv )
// MODE 3: fout = (dinv*t) @ Wn + bias2       (M = 40, fp32 out)

template <int MODE>
__global__ __launch_bounds__(256) void k_agg(const int* __restrict__ rowptr,
                                             const unsigned* __restrict__ csr,
                                             const __half* __restrict__ g,
                                             const float* __restrict__ dinv,
                                             const float* __restrict__ bias,
                                             const float* __restrict__ Wn,
                                             const float* __restrict__ bias2,
                                             void* __restrict__ outv, int n) {
    constexpr int M = (MODE == 3) ? 40 : 64;
    __shared__ float acc[64 * ACCS];               // 16.6 KB
    __shared__ float sW[(MODE >= 2) ? 64 * M : 4];
    int tid = threadIdx.x;
    for (int i = tid; i < 64 * ACCS; i += 256) acc[i] = 0.f;
    if (MODE >= 2) {
        for (int i = tid; i < 16 * M; i += 256)
            ((float4*)sW)[i] = ((const float4*)Wn)[i];
    }
    int n0 = blockIdx.x << 6;
    int nEnd = min(n0 + 64, n);
    int e0 = rowptr[n0], e1 = rowptr[nEnd];
    __syncthreads();

    // ---- edge phase: 8 slots x 32 lanes; lane = half2 feature pair ----
    int slot = tid >> 5, fl = tid & 31;
    int fi = fl << 1;
    int e = e0 + slot;
    for (; e + 8 < e1; e += 16) {                  // 2 gathers in flight
        unsigned u0 = csr[e], u1 = csr[e + 8];
        unsigned w0 = ((const unsigned*)g)[((size_t)(u0 & 0x1FFFF) << 5) + fl];
        unsigned w1 = ((const unsigned*)g)[((size_t)(u1 & 0x1FFFF) << 5) + fl];
        float2 f0 = __half22float2(*(__half2*)&w0);
        float2 f1 = __half22float2(*(__half2*)&w1);
        int l0 = (int)(u0 >> 17) * ACCS, l1 = (int)(u1 >> 17) * ACCS;
        atomicAdd(&acc[l0 + fi], f0.x);
        atomicAdd(&acc[l0 + fi + 1], f0.y);
        atomicAdd(&acc[l1 + fi], f1.x);
        atomicAdd(&acc[l1 + fi + 1], f1.y);
    }
    if (e < e1) {
        unsigned u = csr[e];
        unsigned w = ((const unsigned*)g)[((size_t)(u & 0x1FFFF) << 5) + fl];
        float2 f = __half22float2(*(__half2*)&w);
        int l = (int)(u >> 17) * ACCS;
        atomicAdd(&acc[l + fi], f.x);
        atomicAdd(&acc[l + fi + 1], f.y);
    }
    __syncthreads();

    // ---- self-loop add (one thread per (node, half2-slot); no races) ----
    int nloc = nEnd - n0;
    for (int i = tid; i < (nloc << 5); i += 256) {
        int nl = i >> 5, f = i & 31;
        unsigned w = ((const unsigned*)g)[((size_t)(n0 + nl) << 5) + f];
        float2 v = __half22float2(*(__half2*)&w);
        acc[nl * ACCS + 2 * f]     += v.x;
        acc[nl * ACCS + 2 * f + 1] += v.y;
    }
    __syncthreads();

    if (MODE == 1) {
        for (int i = tid; i < (nloc << 5); i += 256) {
            int nl = i >> 5, f = i & 31;
            float di = dinv[n0 + nl];
            float o0 = fmaxf(acc[nl * ACCS + 2 * f]     * di + bias[2 * f],     0.f) * di;
            float o1 = fmaxf(acc[nl * ACCS + 2 * f + 1] * di + bias[2 * f + 1], 0.f) * di;
            union { unsigned u; __half2 h; } P;
            P.h = __float22half2_rn(make_float2(o0, o1));
            ((unsigned*)outv)[((size_t)(n0 + nl) << 5) + f] = P.u;
        }
        return;
    }

    // ---- pre-transform accumulators in place ----
    for (int i = tid; i < (nloc << 6); i += 256) {
        int nl = i >> 6, f = i & 63;
        float di = dinv[n0 + nl];
        float t = acc[nl * ACCS + f] * di;
        if (MODE == 2) t = fmaxf(t + bias[f], 0.f);
        acc[nl * ACCS + f] = t;
    }
    __syncthreads();

    // ---- matvec: thread = 4 nodes x 4 cols ----
    int rg = tid >> 4;                 // 0..15 -> nodes 4rg..4rg+3
    int cq = (tid & 15) * 4;           // col quad
    if (cq < M) {
        float s[4][4] = {};
#pragma unroll 8
        for (int k = 0; k < 64; ++k) {
            float4 w = *(const float4*)&sW[k * M + cq];
#pragma unroll
            for (int r = 0; r < 4; ++r) {
                float a = acc[(rg * 4 + r) * ACCS + k];
                s[r][0] += a * w.x; s[r][1] += a * w.y;
                s[r][2] += a * w.z; s[r][3] += a * w.w;
            }
        }
#pragma unroll
        for (int r = 0; r < 4; ++r) {
            int node = n0 + rg * 4 + r;
            if (node < n) {
                if (MODE == 2) {
                    float di = dinv[node];
                    union { uint2 u; __half2 h[2]; } P;
                    P.h[0] = __float22half2_rn(make_float2(s[r][0] * di, s[r][1] * di));
                    P.h[1] = __float22half2_rn(make_float2(s[r][2] * di, s[r][3] * di));
                    *(uint2*)((__half*)outv + ((size_t)node << 6) + cq) = P.u;
                } else {
                    float4 o = make_float4(s[r][0] + bias2[cq], s[r][1] + bias2[cq + 1],
                                           s[r][2] + bias2[cq + 2], s[r][3] + bias2[cq + 3]);
                    *(float4*)((float*)outv + (size_t)node * 40 + cq) = o;
                }
            }
        }
    }
}

extern "C" void kernel_launch(void* const* d_in, const int* in_sizes, int n_in,
                              void* d_out, int out_size, void* d_ws, size_t ws_size,
                              hipStream_t stream) {
    const float* x  = (const float*)d_in[0];
    const int*   ei = (const int*)d_in[1];   // [2 x E]: row0 = src, row1 = dst
    const float* W1 = (const float*)d_in[2];
    const float* b1 = (const float*)d_in[3];
    const float* W2 = (const float*)d_in[4];
    const float* b2 = (const float*)d_in[5];
    const float* W3 = (const float*)d_in[6];
    const float* b3 = (const float*)d_in[7];
    float* out = (float*)d_out;

    const int* src = ei;
    const int* dst = ei + NE;

    // workspace: deg | rowptr | cursor | bsum[512] | boff[512] | dinv |
    //            csr[NE] uint | gA half[N*64] | gB half[N*64]
    int*      deg    = (int*)d_ws;
    int*      rowptr = deg + NPAD;
    int*      cursor = rowptr + NPAD;
    int*      bsum   = cursor + NPAD;
    int*      boff   = bsum + 512;
    float*    dinv   = (float*)(boff + 512);
    unsigned* csr    = (unsigned*)(dinv + NPAD);
    __half*   gA     = (__half*)(csr + NE);
    __half*   gB     = gA + (size_t)NN * 64;

    const int B = 256;
    const int gE = (NE + B - 1) / B;
    const int gG = (NN + 31) / 32;
    const int gAgg = (NN + 63) / 64;
    const int nb = (NN + 255) / 256;

    // ---- CSR build + norm ----
    hipMemsetAsync(deg, 0, NPAD * sizeof(int), stream);
    hipMemsetAsync(cursor, 0, NPAD * sizeof(int), stream);
    k_deg_count<<<gE, B, 0, stream>>>(dst, deg, NE);
    k_part<<<nb, 256, 0, stream>>>(deg, bsum, NN);
    k_top<<<1, 512, 0, stream>>>(bsum, boff, nb, rowptr, NN, NE);
    k_write<<<nb, 256, 0, stream>>>(deg, boff, rowptr, dinv, NN);
    for (int p = 0; p < 4; ++p) {
        int lo = (int)((long long)NN * p / 4);
        int hi = (int)((long long)NN * (p + 1) / 4);
        k_fill<<<gE, B, 0, stream>>>(src, dst, rowptr, cursor, csr, NE, lo, hi);
    }

    // ---- layer 1 GEMM (scaled fp16 out): gA = fp16(dinv .* (x @ W1)) ----
    k_gemm1<<<gG, B, 0, stream>>>(x, W1, dinv, gA, NN);
    // ---- AGG1 fused: gB = fp16(dinv .* (relu(dinv*t + b1) @ W2)) ----
    k_agg<2><<<gAgg, B, 0, stream>>>(rowptr, csr, gA, dinv, b1, W2, nullptr, gB, NN);
    // ---- AGG2: gA = fp16(dinv .* relu(dinv*t + b2)) ----
    k_agg<1><<<gAgg, B, 0, stream>>>(rowptr, csr, gB, dinv, b2, nullptr, nullptr, gA, NN);
    // ---- AGG3 fused: out = (dinv*t) @ W3 + b3 ----
    k_agg<3><<<gAgg, B, 0, stream>>>(rowptr, csr, gA, dinv, nullptr, W3, b3, out, NN);
}

// Round 7
// 343.356 us; speedup vs baseline: 5.9258x; 5.9258x over previous
//
#include <hip/hip_runtime.h>
#include <hip/hip_fp16.h>

#define NN 100000
#define NE 1600000
#define NPAD 100352          // NN rounded up to 256
#define ST 68                // LDS t-tile stride (16B-aligned rows, conflict-checked)

// ---------------- CSR build ----------------

__global__ void k_deg_count(const int* __restrict__ dst, int* __restrict__ deg, int e) {
    int i = blockIdx.x * blockDim.x + threadIdx.x;
    if (i < e) atomicAdd(&deg[dst[i]], 1);
}

__global__ __launch_bounds__(256) void k_part(const int* __restrict__ deg,
                                              int* __restrict__ bsum, int n) {
    __shared__ int sp[256];
    int i = blockIdx.x * 256 + threadIdx.x;
    sp[threadIdx.x] = (i < n) ? deg[i] : 0;
    __syncthreads();
    for (int off = 128; off > 0; off >>= 1) {
        if (threadIdx.x < off) sp[threadIdx.x] += sp[threadIdx.x + off];
        __syncthreads();
    }
    if (threadIdx.x == 0) bsum[blockIdx.x] = sp[0];
}

__global__ __launch_bounds__(512) void k_top(const int* __restrict__ bsum,
                                             int* __restrict__ boff, int nb,
                                             int* __restrict__ rowptr, int n, int e) {
    __shared__ int sp[512];
    int t = threadIdx.x;
    int v = (t < nb) ? bsum[t] : 0;
    sp[t] = v;
    __syncthreads();
    for (int off = 1; off < 512; off <<= 1) {
        int u = (t >= off) ? sp[t - off] : 0;
        __syncthreads();
        sp[t] += u;
        __syncthreads();
    }
    if (t < nb) boff[t] = sp[t] - v;
    if (t == 0) rowptr[n] = e;
}

__global__ __launch_bounds__(256) void k_write(const int* __restrict__ deg,
                                               const int* __restrict__ boff,
                                               int* __restrict__ rowptr,
                                               float* __restrict__ dinv, int n) {
    __shared__ int sp[256];
    int t = threadIdx.x;
    int i = blockIdx.x * 256 + t;
    int d = (i < n) ? deg[i] : 0;
    sp[t] = d;
    __syncthreads();
    for (int off = 1; off < 256; off <<= 1) {
        int u = (t >= off) ? sp[t - off] : 0;
        __syncthreads();
        sp[t] += u;
        __syncthreads();
    }
    if (i < n) {
        rowptr[i] = boff[blockIdx.x] + sp[t] - d;   // exclusive
        dinv[i] = rsqrtf((float)(d + 1));           // +1 = self-loop
    }
}

// dst-range-filtered fill: pass p handles d in [lo, hi) so csr writes stay
// inside a ~1.6 MB region the L2s can hold (kills write-thrash).
__global__ void k_fill(const int* __restrict__ src, const int* __restrict__ dst,
                       const int* __restrict__ rowptr, int* __restrict__ cursor,
                       int* __restrict__ csr, int e, int lo, int hi) {
    int i = blockIdx.x * blockDim.x + threadIdx.x;
    if (i < e) {
        int d = dst[i];
        if (d >= lo && d < hi) {
            int idx = rowptr[d] + atomicAdd(&cursor[d], 1);
            csr[idx] = src[i];
        }
    }
}

// ---------------- layer-1 GEMM: g1 = fp16( dinv .* (x @ W1) ) ----------------

__global__ __launch_bounds__(256) void k_gemm1(const float* __restrict__ A,
                                               const float* __restrict__ W,
                                               const float* __restrict__ dinv,
                                               __half* __restrict__ out, int n) {
    __shared__ float sX[32 * 64];
    __shared__ float sW[64 * 64];
    int row0 = blockIdx.x * 32;
    for (int i = threadIdx.x; i < 16 * 64; i += 256)
        ((float4*)sW)[i] = ((const float4*)W)[i];
    for (int i = threadIdx.x; i < 32 * 16; i += 256) {
        int r = i >> 4, c4 = i & 15;
        int row = row0 + r;
        float4 v = (row < n) ? ((const float4*)(A + ((size_t)row << 6)))[c4]
                             : make_float4(0.f, 0.f, 0.f, 0.f);
        ((float4*)sX)[i] = v;
    }
    __syncthreads();

    int ci = (threadIdx.x & 15) * 4;
    int r0 = (threadIdx.x >> 4) * 2;
    float acc[2][4] = {};
#pragma unroll
    for (int k = 0; k < 64; ++k) {
        float a0 = sX[(r0 << 6) + k];
        float a1 = sX[((r0 + 1) << 6) + k];
        float4 w = *(const float4*)&sW[(k << 6) + ci];
        acc[0][0] += a0 * w.x; acc[0][1] += a0 * w.y;
        acc[0][2] += a0 * w.z; acc[0][3] += a0 * w.w;
        acc[1][0] += a1 * w.x; acc[1][1] += a1 * w.y;
        acc[1][2] += a1 * w.z; acc[1][3] += a1 * w.w;
    }
#pragma unroll
    for (int rr = 0; rr < 2; ++rr) {
        int row = row0 + r0 + rr;
        if (row < n) {
            float di = dinv[row];
            union { uint2 u; __half2 h[2]; } P;
            P.h[0] = __float22half2_rn(make_float2(acc[rr][0] * di, acc[rr][1] * di));
            P.h[1] = __float22half2_rn(make_float2(acc[rr][2] * di, acc[rr][3] * di));
            *(uint2*)(out + ((size_t)row << 6) + ci) = P.u;
        }
    }
}

// ---------------- aggregate: 32 nodes/block, 8-lane group per node ----------------
// Lane (ng, fl): node-group ng = lane>>3 owns one node; fl = lane&7 owns a half8
// (16 B) feature slice. Group loops the node's edges serially, 4 gathers in
// flight; NO cross-lane reduce (features disjoint).
// t[d] = sum_{s in N(d)} g[s] + g[d]             (g = dinv .* h)
// MODE 1: gout = fp16( relu(dinv*t + bias) * dinv )           [zero LDS ops]
// MODE 2: h = relu(dinv*t + bias); gout = fp16( (h @ Wn) * dinv )
// MODE 3: fout = (dinv*t) @ Wn + bias2            (M = 40, fp32 out)

#define ACC8(r) { \
    const __half2* hh_ = (const __half2*)&(r); \
    float2 f_; \
    f_ = __half22float2(hh_[0]); a[0].x += f_.x; a[0].y += f_.y; \
    f_ = __half22float2(hh_[1]); a[1].x += f_.x; a[1].y += f_.y; \
    f_ = __half22float2(hh_[2]); a[2].x += f_.x; a[2].y += f_.y; \
    f_ = __half22float2(hh_[3]); a[3].x += f_.x; a[3].y += f_.y; }

template <int MODE>
__global__ __launch_bounds__(256) void k_agg(const int* __restrict__ rowptr,
                                             const int* __restrict__ csr,
                                             const __half* __restrict__ g,
                                             const float* __restrict__ dinv,
                                             const float* __restrict__ bias,
                                             const float* __restrict__ Wn,
                                             const float* __restrict__ bias2,
                                             void* __restrict__ outv, int n) {
    constexpr int M = (MODE == 3) ? 40 : 64;
    __shared__ float sW[(MODE >= 2) ? 64 * M : 1];
    __shared__ float sT[(MODE >= 2) ? 32 * ST : 1];
    int tid = threadIdx.x;
    if (MODE >= 2) {
        for (int i = tid; i < 16 * M; i += 256)
            ((float4*)sW)[i] = ((const float4*)Wn)[i];
    }
    int n0 = blockIdx.x << 5;
    int lane = tid & 63, wid = tid >> 6;
    int ng = lane >> 3, fl = lane & 7;
    int nl = (wid << 3) + ng;              // block-local node 0..31
    int node = n0 + nl;
    bool valid = node < n;
    const uint4* g4 = (const uint4*)g;     // one row = 8 uint4 (64 halves)

    int beg = 0, end = 0;
    if (valid) { beg = rowptr[node]; end = rowptr[node + 1]; }
    float2 a[4] = {};
    int j = beg;
    for (; j + 4 <= end; j += 4) {         // 4 independent gathers in flight
        int s0 = csr[j], s1 = csr[j + 1], s2 = csr[j + 2], s3 = csr[j + 3];
        uint4 r0 = g4[((size_t)s0 << 3) + fl];
        uint4 r1 = g4[((size_t)s1 << 3) + fl];
        uint4 r2 = g4[((size_t)s2 << 3) + fl];
        uint4 r3 = g4[((size_t)s3 << 3) + fl];
        ACC8(r0); ACC8(r1); ACC8(r2); ACC8(r3);
    }
    for (; j < end; ++j) {
        int s = csr[j];
        uint4 r = g4[((size_t)s << 3) + fl];
        ACC8(r);
    }
    if (valid) {                           // self-loop
        uint4 r = g4[((size_t)node << 3) + fl];
        ACC8(r);
    }
    float di = valid ? dinv[node] : 0.f;
    float t[8] = { a[0].x, a[0].y, a[1].x, a[1].y, a[2].x, a[2].y, a[3].x, a[3].y };

    if (MODE == 1) {
        if (valid) {
            float4 b0 = *(const float4*)(bias + (fl << 3));
            float4 b1 = *(const float4*)(bias + (fl << 3) + 4);
            float bv[8] = { b0.x, b0.y, b0.z, b0.w, b1.x, b1.y, b1.z, b1.w };
            union { uint4 u; __half2 h[4]; } P;
#pragma unroll
            for (int k = 0; k < 4; ++k) {
                float o0 = fmaxf(t[2 * k]     * di + bv[2 * k],     0.f) * di;
                float o1 = fmaxf(t[2 * k + 1] * di + bv[2 * k + 1], 0.f) * di;
                P.h[k] = __float22half2_rn(make_float2(o0, o1));
            }
            ((uint4*)outv)[((size_t)node << 3) + fl] = P.u;
        }
        return;
    }

    // MODE 2/3: stash transformed row slice into sT
    {
        float4 b0 = make_float4(0.f, 0.f, 0.f, 0.f), b1 = b0;
        if (MODE == 2) {
            b0 = *(const float4*)(bias + (fl << 3));
            b1 = *(const float4*)(bias + (fl << 3) + 4);
        }
        float bv[8] = { b0.x, b0.y, b0.z, b0.w, b1.x, b1.y, b1.z, b1.w };
        float* row = &sT[nl * ST + (fl << 3)];
#pragma unroll
        for (int k = 0; k < 8; ++k) {
            float v = t[k] * di;
            if (MODE == 2) v = fmaxf(v + bv[k], 0.f);
            row[k] = v;
        }
    }
    __syncthreads();

    // matvec over the 32 staged rows: thread = 2 nodes x 4 cols
    int rg = tid >> 4;                 // 0..15 -> nodes 2rg, 2rg+1
    int cq = (tid & 15) << 2;          // col quad
    if (cq < M) {
        float s0[4] = {}, s1[4] = {};
#pragma unroll 8
        for (int k = 0; k < 64; ++k) {
            float4 w = *(const float4*)&sW[k * M + cq];
            float a0 = sT[(rg * 2) * ST + k];
            float a1 = sT[(rg * 2 + 1) * ST + k];
            s0[0] += a0 * w.x; s0[1] += a0 * w.y; s0[2] += a0 * w.z; s0[3] += a0 * w.w;
            s1[0] += a1 * w.x; s1[1] += a1 * w.y; s1[2] += a1 * w.z; s1[3] += a1 * w.w;
        }
#pragma unroll
        for (int r = 0; r < 2; ++r) {
            float* s = (r == 0) ? s0 : s1;
            int node2 = n0 + rg * 2 + r;
            if (node2 < n) {
                if (MODE == 2) {
                    float d2 = dinv[node2];
                    union { uint2 u; __half2 h[2]; } P;
                    P.h[0] = __float22half2_rn(make_float2(s[0] * d2, s[1] * d2));
                    P.h[1] = __float22half2_rn(make_float2(s[2] * d2, s[3] * d2));
                    *(uint2*)((__half*)outv + ((size_t)node2 << 6) + cq) = P.u;
                } else {
                    float4 o = make_float4(s[0] + bias2[cq],     s[1] + bias2[cq + 1],
                                           s[2] + bias2[cq + 2], s[3] + bias2[cq + 3]);
                    *(float4*)((float*)outv + (size_t)node2 * 40 + cq) = o;
                }
            }
        }
    }
}

extern "C" void kernel_launch(void* const* d_in, const int* in_sizes, int n_in,
                              void* d_out, int out_size, void* d_ws, size_t ws_size,
                              hipStream_t stream) {
    const float* x  = (const float*)d_in[0];
    const int*   ei = (const int*)d_in[1];   // [2 x E]: row0 = src, row1 = dst
    const float* W1 = (const float*)d_in[2];
    const float* b1 = (const float*)d_in[3];
    const float* W2 = (const float*)d_in[4];
    const float* b2 = (const float*)d_in[5];
    const float* W3 = (const float*)d_in[6];
    const float* b3 = (const float*)d_in[7];
    float* out = (float*)d_out;

    const int* src = ei;
    const int* dst = ei + NE;

    // workspace: deg | rowptr | cursor | bsum[512] | boff[512] | dinv |
    //            csr[NE] int | gA half[N*64] | gB half[N*64]
    int*    deg    = (int*)d_ws;
    int*    rowptr = deg + NPAD;
    int*    cursor = rowptr + NPAD;
    int*    bsum   = cursor + NPAD;
    int*    boff   = bsum + 512;
    float*  dinv   = (float*)(boff + 512);
    int*    csr    = (int*)(dinv + NPAD);
    __half* gA     = (__half*)(csr + NE);
    __half* gB     = gA + (size_t)NN * 64;

    const int B = 256;
    const int gE = (NE + B - 1) / B;
    const int gG = (NN + 31) / 32;
    const int gAgg = (NN + 31) / 32;      // 32 nodes per block
    const int nb = (NN + 255) / 256;

    // ---- CSR build + norm ----
    hipMemsetAsync(deg, 0, NPAD * sizeof(int), stream);
    hipMemsetAsync(cursor, 0, NPAD * sizeof(int), stream);
    k_deg_count<<<gE, B, 0, stream>>>(dst, deg, NE);
    k_part<<<nb, 256, 0, stream>>>(deg, bsum, NN);
    k_top<<<1, 512, 0, stream>>>(bsum, boff, nb, rowptr, NN, NE);
    k_write<<<nb, 256, 0, stream>>>(deg, boff, rowptr, dinv, NN);
    for (int p = 0; p < 4; ++p) {
        int lo = (int)((long long)NN * p / 4);
        int hi = (int)((long long)NN * (p + 1) / 4);
        k_fill<<<gE, B, 0, stream>>>(src, dst, rowptr, cursor, csr, NE, lo, hi);
    }

    // ---- layer 1 GEMM (scaled fp16 out): gA = fp16(dinv .* (x @ W1)) ----
    k_gemm1<<<gG, B, 0, stream>>>(x, W1, dinv, gA, NN);
    // ---- AGG1 fused: gB = fp16(dinv .* (relu(dinv*t + b1) @ W2)) ----
    k_agg<2><<<gAgg, B, 0, stream>>>(rowptr, csr, gA, dinv, b1, W2, nullptr, gB, NN);
    // ---- AGG2: gA = fp16(dinv .* relu(dinv*t + b2)) ----
    k_agg<1><<<gAgg, B, 0, stream>>>(rowptr, csr, gB, dinv, b2, nullptr, nullptr, gA, NN);
    // ---- AGG3 fused: out = (dinv*t) @ W3 + b3 ----
    k_agg<3><<<gAgg, B, 0, stream>>>(rowptr, csr, gA, dinv, nullptr, W3, b3, out, NN);
}

// Round 8
// 308.643 us; speedup vs baseline: 6.5922x; 1.1125x over previous
//
#include <hip/hip_runtime.h>
#include <hip/hip_fp16.h>

#define NN 100000
#define NE 1600000
#define NPAD 100352          // NN rounded up to 256
#define ST 68                // LDS t-tile stride (16B-aligned rows, conflict-checked)
#define SXS 68               // gemm1 sX stride: 68%32=4 -> r0-groups hit distinct banks

// ---------------- CSR build ----------------

__global__ void k_deg_count(const int* __restrict__ dst, int* __restrict__ deg, int e) {
    int i = blockIdx.x * blockDim.x + threadIdx.x;
    if (i < e) atomicAdd(&deg[dst[i]], 1);
}

__global__ __launch_bounds__(256) void k_part(const int* __restrict__ deg,
                                              int* __restrict__ bsum, int n) {
    __shared__ int sp[256];
    int i = blockIdx.x * 256 + threadIdx.x;
    sp[threadIdx.x] = (i < n) ? deg[i] : 0;
    __syncthreads();
    for (int off = 128; off > 0; off >>= 1) {
        if (threadIdx.x < off) sp[threadIdx.x] += sp[threadIdx.x + off];
        __syncthreads();
    }
    if (threadIdx.x == 0) bsum[blockIdx.x] = sp[0];
}

__global__ __launch_bounds__(512) void k_top(const int* __restrict__ bsum,
                                             int* __restrict__ boff, int nb,
                                             int* __restrict__ rowptr, int n, int e) {
    __shared__ int sp[512];
    int t = threadIdx.x;
    int v = (t < nb) ? bsum[t] : 0;
    sp[t] = v;
    __syncthreads();
    for (int off = 1; off < 512; off <<= 1) {
        int u = (t >= off) ? sp[t - off] : 0;
        __syncthreads();
        sp[t] += u;
        __syncthreads();
    }
    if (t < nb) boff[t] = sp[t] - v;
    if (t == 0) rowptr[n] = e;
}

__global__ __launch_bounds__(256) void k_write(const int* __restrict__ deg,
                                               const int* __restrict__ boff,
                                               int* __restrict__ rowptr,
                                               float* __restrict__ dinv, int n) {
    __shared__ int sp[256];
    int t = threadIdx.x;
    int i = blockIdx.x * 256 + t;
    int d = (i < n) ? deg[i] : 0;
    sp[t] = d;
    __syncthreads();
    for (int off = 1; off < 256; off <<= 1) {
        int u = (t >= off) ? sp[t - off] : 0;
        __syncthreads();
        sp[t] += u;
        __syncthreads();
    }
    if (i < n) {
        rowptr[i] = boff[blockIdx.x] + sp[t] - d;   // exclusive
        dinv[i] = rsqrtf((float)(d + 1));           // +1 = self-loop
    }
}

// dst-range-filtered fill: pass p handles d in [lo, hi) so csr writes stay
// inside a ~1.6 MB region the L2s can hold (kills write-thrash).
__global__ void k_fill(const int* __restrict__ src, const int* __restrict__ dst,
                       const int* __restrict__ rowptr, int* __restrict__ cursor,
                       int* __restrict__ csr, int e, int lo, int hi) {
    int i = blockIdx.x * blockDim.x + threadIdx.x;
    if (i < e) {
        int d = dst[i];
        if (d >= lo && d < hi) {
            int idx = rowptr[d] + atomicAdd(&cursor[d], 1);
            csr[idx] = src[i];
        }
    }
}

// ---------------- layer-1 GEMM: g1 = fp16( dinv .* (x @ W1) ) ----------------
// 32 rows/block; thread = 2 rows x 4 cols. sX stride 68: bank = (4*r0+k)%32,
// the 4 r0-groups per wave land on distinct banks (same-r0 lanes broadcast).

__global__ __launch_bounds__(256, 4) void k_gemm1(const float* __restrict__ A,
                                                  const float* __restrict__ W,
                                                  const float* __restrict__ dinv,
                                                  __half* __restrict__ out, int n) {
    __shared__ float sX[32 * SXS];
    __shared__ float sW[64 * 64];
    int row0 = blockIdx.x * 32;
    for (int i = threadIdx.x; i < 16 * 64; i += 256)
        ((float4*)sW)[i] = ((const float4*)W)[i];
    for (int i = threadIdx.x; i < 32 * 16; i += 256) {
        int r = i >> 4, c4 = i & 15;
        int row = row0 + r;
        float4 v = (row < n) ? ((const float4*)(A + ((size_t)row << 6)))[c4]
                             : make_float4(0.f, 0.f, 0.f, 0.f);
        *(float4*)&sX[r * SXS + (c4 << 2)] = v;
    }
    __syncthreads();

    int ci = (threadIdx.x & 15) * 4;
    int r0 = (threadIdx.x >> 4) * 2;
    float acc[2][4] = {};
#pragma unroll 16
    for (int k = 0; k < 64; ++k) {
        float a0 = sX[r0 * SXS + k];
        float a1 = sX[(r0 + 1) * SXS + k];
        float4 w = *(const float4*)&sW[(k << 6) + ci];
        acc[0][0] += a0 * w.x; acc[0][1] += a0 * w.y;
        acc[0][2] += a0 * w.z; acc[0][3] += a0 * w.w;
        acc[1][0] += a1 * w.x; acc[1][1] += a1 * w.y;
        acc[1][2] += a1 * w.z; acc[1][3] += a1 * w.w;
    }
#pragma unroll
    for (int rr = 0; rr < 2; ++rr) {
        int row = row0 + r0 + rr;
        if (row < n) {
            float di = dinv[row];
            union { uint2 u; __half2 h[2]; } P;
            P.h[0] = __float22half2_rn(make_float2(acc[rr][0] * di, acc[rr][1] * di));
            P.h[1] = __float22half2_rn(make_float2(acc[rr][2] * di, acc[rr][3] * di));
            *(uint2*)(out + ((size_t)row << 6) + ci) = P.u;
        }
    }
}

// ---------------- aggregate: 32 nodes/block, 8-lane group per node ----------------
// Lane (ng, fl): node-group ng = lane>>3 owns one node; fl = lane&7 owns a half8
// (16 B) feature slice. Group loops the node's edges serially, 4 gathers in
// flight; NO cross-lane reduce (features disjoint).
// t[d] = sum_{s in N(d)} g[s] + g[d]             (g = dinv .* h)
// MODE 1: gout = fp16( relu(dinv*t + bias) * dinv )           [zero LDS ops]
// MODE 2: h = relu(dinv*t + bias); gout = fp16( (h @ Wn) * dinv )
// MODE 3: fout = (dinv*t) @ Wn + bias2            (M = 40, fp32 out)

#define ACC8(r) { \
    const __half2* hh_ = (const __half2*)&(r); \
    float2 f_; \
    f_ = __half22float2(hh_[0]); a[0].x += f_.x; a[0].y += f_.y; \
    f_ = __half22float2(hh_[1]); a[1].x += f_.x; a[1].y += f_.y; \
    f_ = __half22float2(hh_[2]); a[2].x += f_.x; a[2].y += f_.y; \
    f_ = __half22float2(hh_[3]); a[3].x += f_.x; a[3].y += f_.y; }

template <int MODE>
__global__ __launch_bounds__(256) void k_agg(const int* __restrict__ rowptr,
                                             const int* __restrict__ csr,
                                             const __half* __restrict__ g,
                                             const float* __restrict__ dinv,
                                             const float* __restrict__ bias,
                                             const float* __restrict__ Wn,
                                             const float* __restrict__ bias2,
                                             void* __restrict__ outv, int n) {
    constexpr int M = (MODE == 3) ? 40 : 64;
    __shared__ float sW[(MODE >= 2) ? 64 * M : 1];
    __shared__ float sT[(MODE >= 2) ? 32 * ST : 1];
    int tid = threadIdx.x;
    if (MODE >= 2) {
        for (int i = tid; i < 16 * M; i += 256)
            ((float4*)sW)[i] = ((const float4*)Wn)[i];
    }
    int n0 = blockIdx.x << 5;
    int lane = tid & 63, wid = tid >> 6;
    int ng = lane >> 3, fl = lane & 7;
    int nl = (wid << 3) + ng;              // block-local node 0..31
    int node = n0 + nl;
    bool valid = node < n;
    const uint4* g4 = (const uint4*)g;     // one row = 8 uint4 (64 halves)

    int beg = 0, end = 0;
    if (valid) { beg = rowptr[node]; end = rowptr[node + 1]; }
    float2 a[4] = {};
    int j = beg;
    for (; j + 4 <= end; j += 4) {         // 4 independent gathers in flight
        int s0 = csr[j], s1 = csr[j + 1], s2 = csr[j + 2], s3 = csr[j + 3];
        uint4 r0 = g4[((size_t)s0 << 3) + fl];
        uint4 r1 = g4[((size_t)s1 << 3) + fl];
        uint4 r2 = g4[((size_t)s2 << 3) + fl];
        uint4 r3 = g4[((size_t)s3 << 3) + fl];
        ACC8(r0); ACC8(r1); ACC8(r2); ACC8(r3);
    }
    for (; j < end; ++j) {
        int s = csr[j];
        uint4 r = g4[((size_t)s << 3) + fl];
        ACC8(r);
    }
    if (valid) {                           // self-loop
        uint4 r = g4[((size_t)node << 3) + fl];
        ACC8(r);
    }
    float di = valid ? dinv[node] : 0.f;
    float t[8] = { a[0].x, a[0].y, a[1].x, a[1].y, a[2].x, a[2].y, a[3].x, a[3].y };

    if (MODE == 1) {
        if (valid) {
            float4 b0 = *(const float4*)(bias + (fl << 3));
            float4 b1 = *(const float4*)(bias + (fl << 3) + 4);
            float bv[8] = { b0.x, b0.y, b0.z, b0.w, b1.x, b1.y, b1.z, b1.w };
            union { uint4 u; __half2 h[4]; } P;
#pragma unroll
            for (int k = 0; k < 4; ++k) {
                float o0 = fmaxf(t[2 * k]     * di + bv[2 * k],     0.f) * di;
                float o1 = fmaxf(t[2 * k + 1] * di + bv[2 * k + 1], 0.f) * di;
                P.h[k] = __float22half2_rn(make_float2(o0, o1));
            }
            ((uint4*)outv)[((size_t)node << 3) + fl] = P.u;
        }
        return;
    }

    // MODE 2/3: stash transformed row slice into sT
    {
        float4 b0 = make_float4(0.f, 0.f, 0.f, 0.f), b1 = b0;
        if (MODE == 2) {
            b0 = *(const float4*)(bias + (fl << 3));
            b1 = *(const float4*)(bias + (fl << 3) + 4);
        }
        float bv[8] = { b0.x, b0.y, b0.z, b0.w, b1.x, b1.y, b1.z, b1.w };
        float* row = &sT[nl * ST + (fl << 3)];
#pragma unroll
        for (int k = 0; k < 8; ++k) {
            float v = t[k] * di;
            if (MODE == 2) v = fmaxf(v + bv[k], 0.f);
            row[k] = v;
        }
    }
    __syncthreads();

    // matvec over the 32 staged rows: thread = 2 nodes x 4 cols
    int rg = tid >> 4;                 // 0..15 -> nodes 2rg, 2rg+1
    int cq = (tid & 15) << 2;          // col quad
    if (cq < M) {
        float s0[4] = {}, s1[4] = {};
#pragma unroll 8
        for (int k = 0; k < 64; ++k) {
            float4 w = *(const float4*)&sW[k * M + cq];
            float a0 = sT[(rg * 2) * ST + k];
            float a1 = sT[(rg * 2 + 1) * ST + k];
            s0[0] += a0 * w.x; s0[1] += a0 * w.y; s0[2] += a0 * w.z; s0[3] += a0 * w.w;
            s1[0] += a1 * w.x; s1[1] += a1 * w.y; s1[2] += a1 * w.z; s1[3] += a1 * w.w;
        }
#pragma unroll
        for (int r = 0; r < 2; ++r) {
            float* s = (r == 0) ? s0 : s1;
            int node2 = n0 + rg * 2 + r;
            if (node2 < n) {
                if (MODE == 2) {
                    float d2 = dinv[node2];
                    union { uint2 u; __half2 h[2]; } P;
                    P.h[0] = __float22half2_rn(make_float2(s[0] * d2, s[1] * d2));
                    P.h[1] = __float22half2_rn(make_float2(s[2] * d2, s[3] * d2));
                    *(uint2*)((__half*)outv + ((size_t)node2 << 6) + cq) = P.u;
                } else {
                    float4 o = make_float4(s[0] + bias2[cq],     s[1] + bias2[cq + 1],
                                           s[2] + bias2[cq + 2], s[3] + bias2[cq + 3]);
                    *(float4*)((float*)outv + (size_t)node2 * 40 + cq) = o;
                }
            }
        }
    }
}

extern "C" void kernel_launch(void* const* d_in, const int* in_sizes, int n_in,
                              void* d_out, int out_size, void* d_ws, size_t ws_size,
                              hipStream_t stream) {
    const float* x  = (const float*)d_in[0];
    const int*   ei = (const int*)d_in[1];   // [2 x E]: row0 = src, row1 = dst
    const float* W1 = (const float*)d_in[2];
    const float* b1 = (const float*)d_in[3];
    const float* W2 = (const float*)d_in[4];
    const float* b2 = (const float*)d_in[5];
    const float* W3 = (const float*)d_in[6];
    const float* b3 = (const float*)d_in[7];
    float* out = (float*)d_out;

    const int* src = ei;
    const int* dst = ei + NE;

    // workspace: deg | rowptr | cursor | bsum[512] | boff[512] | dinv |
    //            csr[NE] int | gA half[N*64] | gB half[N*64]
    int*    deg    = (int*)d_ws;
    int*    rowptr = deg + NPAD;
    int*    cursor = rowptr + NPAD;
    int*    bsum   = cursor + NPAD;
    int*    boff   = bsum + 512;
    float*  dinv   = (float*)(boff + 512);
    int*    csr    = (int*)(dinv + NPAD);
    __half* gA     = (__half*)(csr + NE);
    __half* gB     = gA + (size_t)NN * 64;

    const int B = 256;
    const int gE = (NE + B - 1) / B;
    const int gG = (NN + 31) / 32;
    const int gAgg = (NN + 31) / 32;      // 32 nodes per block
    const int nb = (NN + 255) / 256;

    // ---- CSR build + norm ----
    hipMemsetAsync(deg, 0, NPAD * sizeof(int), stream);
    hipMemsetAsync(cursor, 0, NPAD * sizeof(int), stream);
    k_deg_count<<<gE, B, 0, stream>>>(dst, deg, NE);
    k_part<<<nb, 256, 0, stream>>>(deg, bsum, NN);
    k_top<<<1, 512, 0, stream>>>(bsum, boff, nb, rowptr, NN, NE);
    k_write<<<nb, 256, 0, stream>>>(deg, boff, rowptr, dinv, NN);
    for (int p = 0; p < 4; ++p) {
        int lo = (int)((long long)NN * p / 4);
        int hi = (int)((long long)NN * (p + 1) / 4);
        k_fill<<<gE, B, 0, stream>>>(src, dst, rowptr, cursor, csr, NE, lo, hi);
    }

    // ---- layer 1 GEMM (scaled fp16 out): gA = fp16(dinv .* (x @ W1)) ----
    k_gemm1<<<gG, B, 0, stream>>>(x, W1, dinv, gA, NN);
    // ---- AGG1 fused: gB = fp16(dinv .* (relu(dinv*t + b1) @ W2)) ----
    k_agg<2><<<gAgg, B, 0, stream>>>(rowptr, csr, gA, dinv, b1, W2, nullptr, gB, NN);
    // ---- AGG2: gA = fp16(dinv .* relu(dinv*t + b2)) ----
    k_agg<1><<<gAgg, B, 0, stream>>>(rowptr, csr, gB, dinv, b2, nullptr, nullptr, gA, NN);
    // ---- AGG3 fused: out = (dinv*t) @ W3 + b3 ----
    k_agg<3><<<gAgg, B, 0, stream>>>(rowptr, csr, gA, dinv, nullptr, W3, b3, out, NN);
}

// Round 9
// 292.179 us; speedup vs baseline: 6.9637x; 1.0563x over previous
//
#include <hip/hip_runtime.h>
#include <hip/hip_fp16.h>

#define NN 100000
#define NE 1600000
#define NPAD 100352          // NN rounded up to 256
#define ST 68                // LDS t-tile stride (16B-aligned rows, conflict-checked)
#define SXS 68               // gemm1 sX stride: 68%32=4 -> r0-groups hit distinct banks

// ---------------- CSR build ----------------
// deg8: 8 XCD-private planes (block b -> plane b&7; round-robin dispatch puts
// each plane's atomic lines in ONE XCD's L2 -> no cross-XCD line ping-pong).

__global__ void k_deg_count(const int* __restrict__ dst, int* __restrict__ deg8, int e) {
    int i = blockIdx.x * blockDim.x + threadIdx.x;
    int c = blockIdx.x & 7;
    if (i < e) atomicAdd(&deg8[c * NPAD + dst[i]], 1);
}

// sum the 8 planes -> deg[i]; also per-block total for the scan
__global__ __launch_bounds__(256) void k_part(const int* __restrict__ deg8,
                                              int* __restrict__ deg,
                                              int* __restrict__ bsum, int n) {
    __shared__ int sp[256];
    int i = blockIdx.x * 256 + threadIdx.x;
    int s = 0;
    if (i < n) {
#pragma unroll
        for (int c = 0; c < 8; ++c) s += deg8[c * NPAD + i];
        deg[i] = s;
    }
    sp[threadIdx.x] = s;
    __syncthreads();
    for (int off = 128; off > 0; off >>= 1) {
        if (threadIdx.x < off) sp[threadIdx.x] += sp[threadIdx.x + off];
        __syncthreads();
    }
    if (threadIdx.x == 0) bsum[blockIdx.x] = sp[0];
}

__global__ __launch_bounds__(512) void k_top(const int* __restrict__ bsum,
                                             int* __restrict__ boff, int nb,
                                             int* __restrict__ rowptr, int n, int e) {
    __shared__ int sp[512];
    int t = threadIdx.x;
    int v = (t < nb) ? bsum[t] : 0;
    sp[t] = v;
    __syncthreads();
    for (int off = 1; off < 512; off <<= 1) {
        int u = (t >= off) ? sp[t - off] : 0;
        __syncthreads();
        sp[t] += u;
        __syncthreads();
    }
    if (t < nb) boff[t] = sp[t] - v;
    if (t == 0) rowptr[n] = e;
}

// rowptr + dinv + per-plane fill cursors (cursor8[c][i] = rowptr[i] + prefix(deg8[<c][i]))
__global__ __launch_bounds__(256) void k_write(const int* __restrict__ deg,
                                               const int* __restrict__ deg8,
                                               const int* __restrict__ boff,
                                               int* __restrict__ rowptr,
                                               int* __restrict__ cursor8,
                                               float* __restrict__ dinv, int n) {
    __shared__ int sp[256];
    int t = threadIdx.x;
    int i = blockIdx.x * 256 + t;
    int d = (i < n) ? deg[i] : 0;
    sp[t] = d;
    __syncthreads();
    for (int off = 1; off < 256; off <<= 1) {
        int u = (t >= off) ? sp[t - off] : 0;
        __syncthreads();
        sp[t] += u;
        __syncthreads();
    }
    if (i < n) {
        int rp = boff[blockIdx.x] + sp[t] - d;      // exclusive
        rowptr[i] = rp;
        dinv[i] = rsqrtf((float)(d + 1));           // +1 = self-loop
        int run = rp;
#pragma unroll
        for (int c = 0; c < 8; ++c) {
            cursor8[c * NPAD + i] = run;
            run += deg8[c * NPAD + i];
        }
    }
}

// dst-range-filtered fill (4 passes keep csr store region L2-resident);
// plane-private cursors kill cross-XCD atomic bouncing.
__global__ void k_fill(const int* __restrict__ src, const int* __restrict__ dst,
                       int* __restrict__ cursor8,
                       int* __restrict__ csr, int e, int lo, int hi) {
    int i = blockIdx.x * blockDim.x + threadIdx.x;
    int c = blockIdx.x & 7;
    if (i < e) {
        int d = dst[i];
        if (d >= lo && d < hi) {
            int idx = atomicAdd(&cursor8[c * NPAD + d], 1);
            csr[idx] = src[i];
        }
    }
}

// ---------------- layer-1 GEMM: g1 = fp16( dinv .* (x @ W1) ) ----------------
// 32 rows/block; thread = 2 rows x 4 cols. sX stride 68: bank = (4*r0+k)%32,
// the 4 r0-groups per wave land on distinct banks (same-r0 lanes broadcast).

__global__ __launch_bounds__(256, 4) void k_gemm1(const float* __restrict__ A,
                                                  const float* __restrict__ W,
                                                  const float* __restrict__ dinv,
                                                  __half* __restrict__ out, int n) {
    __shared__ float sX[32 * SXS];
    __shared__ float sW[64 * 64];
    int row0 = blockIdx.x * 32;
    for (int i = threadIdx.x; i < 16 * 64; i += 256)
        ((float4*)sW)[i] = ((const float4*)W)[i];
    for (int i = threadIdx.x; i < 32 * 16; i += 256) {
        int r = i >> 4, c4 = i & 15;
        int row = row0 + r;
        float4 v = (row < n) ? ((const float4*)(A + ((size_t)row << 6)))[c4]
                             : make_float4(0.f, 0.f, 0.f, 0.f);
        *(float4*)&sX[r * SXS + (c4 << 2)] = v;
    }
    __syncthreads();

    int ci = (threadIdx.x & 15) * 4;
    int r0 = (threadIdx.x >> 4) * 2;
    float acc[2][4] = {};
#pragma unroll 16
    for (int k = 0; k < 64; ++k) {
        float a0 = sX[r0 * SXS + k];
        float a1 = sX[(r0 + 1) * SXS + k];
        float4 w = *(const float4*)&sW[(k << 6) + ci];
        acc[0][0] += a0 * w.x; acc[0][1] += a0 * w.y;
        acc[0][2] += a0 * w.z; acc[0][3] += a0 * w.w;
        acc[1][0] += a1 * w.x; acc[1][1] += a1 * w.y;
        acc[1][2] += a1 * w.z; acc[1][3] += a1 * w.w;
    }
#pragma unroll
    for (int rr = 0; rr < 2; ++rr) {
        int row = row0 + r0 + rr;
        if (row < n) {
            float di = dinv[row];
            union { uint2 u; __half2 h[2]; } P;
            P.h[0] = __float22half2_rn(make_float2(acc[rr][0] * di, acc[rr][1] * di));
            P.h[1] = __float22half2_rn(make_float2(acc[rr][2] * di, acc[rr][3] * di));
            *(uint2*)(out + ((size_t)row << 6) + ci) = P.u;
        }
    }
}

// ---------------- aggregate: 32 nodes/block, 8-lane group per node ----------------
// t[d] = sum_{s in N(d)} g[s] + g[d]             (g = dinv .* h)
// MODE 1: gout = fp16( relu(dinv*t + bias) * dinv )           [zero LDS ops]
// MODE 2: h = relu(dinv*t + bias); gout = fp16( (h @ Wn) * dinv )
// MODE 3: fout = (dinv*t) @ Wn + bias2            (M = 40, fp32 out)

#define ACC8(r) { \
    const __half2* hh_ = (const __half2*)&(r); \
    float2 f_; \
    f_ = __half22float2(hh_[0]); a[0].x += f_.x; a[0].y += f_.y; \
    f_ = __half22float2(hh_[1]); a[1].x += f_.x; a[1].y += f_.y; \
    f_ = __half22float2(hh_[2]); a[2].x += f_.x; a[2].y += f_.y; \
    f_ = __half22float2(hh_[3]); a[3].x += f_.x; a[3].y += f_.y; }

template <int MODE>
__global__ __launch_bounds__(256) void k_agg(const int* __restrict__ rowptr,
                                             const int* __restrict__ csr,
                                             const __half* __restrict__ g,
                                             const float* __restrict__ dinv,
                                             const float* __restrict__ bias,
                                             const float* __restrict__ Wn,
                                             const float* __restrict__ bias2,
                                             void* __restrict__ outv, int n) {
    constexpr int M = (MODE == 3) ? 40 : 64;
    __shared__ float sW[(MODE >= 2) ? 64 * M : 1];
    __shared__ float sT[(MODE >= 2) ? 32 * ST : 1];
    int tid = threadIdx.x;
    if (MODE >= 2) {
        for (int i = tid; i < 16 * M; i += 256)
            ((float4*)sW)[i] = ((const float4*)Wn)[i];
    }
    int n0 = blockIdx.x << 5;
    int lane = tid & 63, wid = tid >> 6;
    int ng = lane >> 3, fl = lane & 7;
    int nl = (wid << 3) + ng;              // block-local node 0..31
    int node = n0 + nl;
    bool valid = node < n;
    const uint4* g4 = (const uint4*)g;     // one row = 8 uint4 (64 halves)

    int beg = 0, end = 0;
    if (valid) { beg = rowptr[node]; end = rowptr[node + 1]; }
    float2 a[4] = {};
    int j = beg;
    for (; j + 4 <= end; j += 4) {         // 4 independent gathers in flight
        int s0 = csr[j], s1 = csr[j + 1], s2 = csr[j + 2], s3 = csr[j + 3];
        uint4 r0 = g4[((size_t)s0 << 3) + fl];
        uint4 r1 = g4[((size_t)s1 << 3) + fl];
        uint4 r2 = g4[((size_t)s2 << 3) + fl];
        uint4 r3 = g4[((size_t)s3 << 3) + fl];
        ACC8(r0); ACC8(r1); ACC8(r2); ACC8(r3);
    }
    for (; j < end; ++j) {
        int s = csr[j];
        uint4 r = g4[((size_t)s << 3) + fl];
        ACC8(r);
    }
    if (valid) {                           // self-loop
        uint4 r = g4[((size_t)node << 3) + fl];
        ACC8(r);
    }
    float di = valid ? dinv[node] : 0.f;
    float t[8] = { a[0].x, a[0].y, a[1].x, a[1].y, a[2].x, a[2].y, a[3].x, a[3].y };

    if (MODE == 1) {
        if (valid) {
            float4 b0 = *(const float4*)(bias + (fl << 3));
            float4 b1 = *(const float4*)(bias + (fl << 3) + 4);
            float bv[8] = { b0.x, b0.y, b0.z, b0.w, b1.x, b1.y, b1.z, b1.w };
            union { uint4 u; __half2 h[4]; } P;
#pragma unroll
            for (int k = 0; k < 4; ++k) {
                float o0 = fmaxf(t[2 * k]     * di + bv[2 * k],     0.f) * di;
                float o1 = fmaxf(t[2 * k + 1] * di + bv[2 * k + 1], 0.f) * di;
                P.h[k] = __float22half2_rn(make_float2(o0, o1));
            }
            ((uint4*)outv)[((size_t)node << 3) + fl] = P.u;
        }
        return;
    }

    // MODE 2/3: stash transformed row slice into sT
    {
        float4 b0 = make_float4(0.f, 0.f, 0.f, 0.f), b1 = b0;
        if (MODE == 2) {
            b0 = *(const float4*)(bias + (fl << 3));
            b1 = *(const float4*)(bias + (fl << 3) + 4);
        }
        float bv[8] = { b0.x, b0.y, b0.z, b0.w, b1.x, b1.y, b1.z, b1.w };
        float* row = &sT[nl * ST + (fl << 3)];
#pragma unroll
        for (int k = 0; k < 8; ++k) {
            float v = t[k] * di;
            if (MODE == 2) v = fmaxf(v + bv[k], 0.f);
            row[k] = v;
        }
    }
    __syncthreads();

    // matvec over the 32 staged rows: thread = 2 nodes x 4 cols
    int rg = tid >> 4;                 // 0..15 -> nodes 2rg, 2rg+1
    int cq = (tid & 15) << 2;          // col quad
    if (cq < M) {
        float s0[4] = {}, s1[4] = {};
#pragma unroll 8
        for (int k = 0; k < 64; ++k) {
            float4 w = *(const float4*)&sW[k * M + cq];
            float a0 = sT[(rg * 2) * ST + k];
            float a1 = sT[(rg * 2 + 1) * ST + k];
            s0[0] += a0 * w.x; s0[1] += a0 * w.y; s0[2] += a0 * w.z; s0[3] += a0 * w.w;
            s1[0] += a1 * w.x; s1[1] += a1 * w.y; s1[2] += a1 * w.z; s1[3] += a1 * w.w;
        }
#pragma unroll
        for (int r = 0; r < 2; ++r) {
            float* s = (r == 0) ? s0 : s1;
            int node2 = n0 + rg * 2 + r;
            if (node2 < n) {
                if (MODE == 2) {
                    float d2 = dinv[node2];
                    union { uint2 u; __half2 h[2]; } P;
                    P.h[0] = __float22half2_rn(make_float2(s[0] * d2, s[1] * d2));
                    P.h[1] = __float22half2_rn(make_float2(s[2] * d2, s[3] * d2));
                    *(uint2*)((__half*)outv + ((size_t)node2 << 6) + cq) = P.u;
                } else {
                    float4 o = make_float4(s[0] + bias2[cq],     s[1] + bias2[cq + 1],
                                           s[2] + bias2[cq + 2], s[3] + bias2[cq + 3]);
                    *(float4*)((float*)outv + (size_t)node2 * 40 + cq) = o;
                }
            }
        }
    }
}

extern "C" void kernel_launch(void* const* d_in, const int* in_sizes, int n_in,
                              void* d_out, int out_size, void* d_ws, size_t ws_size,
                              hipStream_t stream) {
    const float* x  = (const float*)d_in[0];
    const int*   ei = (const int*)d_in[1];   // [2 x E]: row0 = src, row1 = dst
    const float* W1 = (const float*)d_in[2];
    const float* b1 = (const float*)d_in[3];
    const float* W2 = (const float*)d_in[4];
    const float* b2 = (const float*)d_in[5];
    const float* W3 = (const float*)d_in[6];
    const float* b3 = (const float*)d_in[7];
    float* out = (float*)d_out;

    const int* src = ei;
    const int* dst = ei + NE;

    // workspace: deg8[8*NPAD] | cursor8[8*NPAD] | deg[NPAD] | rowptr[NPAD] |
    //            bsum[512] | boff[512] | dinv[NPAD] | csr[NE] | gA | gB (half)
    int*    deg8    = (int*)d_ws;
    int*    cursor8 = deg8 + 8 * NPAD;
    int*    deg     = cursor8 + 8 * NPAD;
    int*    rowptr  = deg + NPAD;
    int*    bsum    = rowptr + NPAD;
    int*    boff    = bsum + 512;
    float*  dinv    = (float*)(boff + 512);
    int*    csr     = (int*)(dinv + NPAD);
    __half* gA      = (__half*)(csr + NE);
    __half* gB      = gA + (size_t)NN * 64;

    const int B = 256;
    const int gE = (NE + B - 1) / B;
    const int gG = (NN + 31) / 32;
    const int gAgg = (NN + 31) / 32;      // 32 nodes per block
    const int nb = (NN + 255) / 256;

    // ---- CSR build + norm ----
    hipMemsetAsync(deg8, 0, 8 * NPAD * sizeof(int), stream);
    k_deg_count<<<gE, B, 0, stream>>>(dst, deg8, NE);
    k_part<<<nb, 256, 0, stream>>>(deg8, deg, bsum, NN);
    k_top<<<1, 512, 0, stream>>>(bsum, boff, nb, rowptr, NN, NE);
    k_write<<<nb, 256, 0, stream>>>(deg, deg8, boff, rowptr, cursor8, dinv, NN);
    for (int p = 0; p < 4; ++p) {
        int lo = (int)((long long)NN * p / 4);
        int hi = (int)((long long)NN * (p + 1) / 4);
        k_fill<<<gE, B, 0, stream>>>(src, dst, cursor8, csr, NE, lo, hi);
    }

    // ---- layer 1 GEMM (scaled fp16 out): gA = fp16(dinv .* (x @ W1)) ----
    k_gemm1<<<gG, B, 0, stream>>>(x, W1, dinv, gA, NN);
    // ---- AGG1 fused: gB = fp16(dinv .* (relu(dinv*t + b1) @ W2)) ----
    k_agg<2><<<gAgg, B, 0, stream>>>(rowptr, csr, gA, dinv, b1, W2, nullptr, gB, NN);
    // ---- AGG2: gA = fp16(dinv .* relu(dinv*t + b2)) ----
    k_agg<1><<<gAgg, B, 0, stream>>>(rowptr, csr, gB, dinv, b2, nullptr, nullptr, gA, NN);
    // ---- AGG3 fused: out = (dinv*t) @ W3 + b3 ----
    k_agg<3><<<gAgg, B, 0, stream>>>(rowptr, csr, gA, dinv, nullptr, W3, b3, out, NN);
}

// Round 10
// 184.474 us; speedup vs baseline: 11.0295x; 1.5839x over previous
//
#include <hip/hip_runtime.h>
#include <hip/hip_fp16.h>

#define NN 100000
#define NE 1600000
#define NPAD 100352          // NN rounded up to 256
#define ST 68                // LDS t-tile stride (16B-aligned rows, conflict-checked)
#define SXS 68               // gemm1 sX stride: 68%32=4 -> r0-groups hit distinct banks
#define NB 256               // hist/scatter blocks (NE % NB == 0 -> 6250 edges each)
#define CE (NE / NB)
#define D1 391               // dst>>8 buckets (99999>>8 = 390)
#define L1 (D1 * NB)         // flattened hist size = 100096

// ================= CSR build: bucket sort, ZERO scattered global atomics ======
// (scattered global atomics are memory-side RMWs on gfx950 -- ~26M/s drain,
//  measured R8/R9: deg_count 62us, WRITE_SIZE = 32B per atomic)

// per-block LDS histogram of dst>>8 -> H[d*NB + b]
__global__ __launch_bounds__(256) void k_hist(const int* __restrict__ dst,
                                              unsigned* __restrict__ H) {
    __shared__ unsigned h[D1];
    int b = blockIdx.x, t = threadIdx.x;
    for (int i = t; i < D1; i += 256) h[i] = 0;
    __syncthreads();
    int beg = b * CE, end = beg + CE;
    for (int i = beg + t; i < end; i += 256)
        atomicAdd(&h[((unsigned)dst[i]) >> 8], 1u);
    __syncthreads();
    for (int d = t; d < D1; d += 256) H[d * NB + b] = h[d];
}

// hierarchical exclusive scan of H (length L1): A = block sums, B = scan sums,
// C = apply (in place).
__global__ __launch_bounds__(256) void k_scanA(const unsigned* __restrict__ in,
                                               unsigned* __restrict__ bsum, int L) {
    __shared__ unsigned sp[256];
    int i = blockIdx.x * 256 + threadIdx.x;
    sp[threadIdx.x] = (i < L) ? in[i] : 0;
    __syncthreads();
    for (int off = 128; off > 0; off >>= 1) {
        if (threadIdx.x < off) sp[threadIdx.x] += sp[threadIdx.x + off];
        __syncthreads();
    }
    if (threadIdx.x == 0) bsum[blockIdx.x] = sp[0];
}

__global__ __launch_bounds__(512) void k_scanB(unsigned* __restrict__ bsum, int nb) {
    __shared__ unsigned sp[512];
    int t = threadIdx.x;
    unsigned v = (t < nb) ? bsum[t] : 0;
    sp[t] = v;
    __syncthreads();
    for (int off = 1; off < 512; off <<= 1) {
        unsigned u = (t >= off) ? sp[t - off] : 0;
        __syncthreads();
        sp[t] += u;
        __syncthreads();
    }
    if (t < nb) bsum[t] = sp[t] - v;      // exclusive
}

__global__ __launch_bounds__(256) void k_scanC(unsigned* __restrict__ H,
                                               const unsigned* __restrict__ bsum, int L) {
    __shared__ unsigned sp[256];
    int t = threadIdx.x, i = blockIdx.x * 256 + t;
    unsigned v = (i < L) ? H[i] : 0;
    sp[t] = v;
    __syncthreads();
    for (int off = 1; off < 256; off <<= 1) {
        unsigned u = (t >= off) ? sp[t - off] : 0;
        __syncthreads();
        sp[t] += u;
        __syncthreads();
    }
    if (i < L) H[i] = bsum[blockIdx.x] + sp[t] - v;
}

// scatter edges into bucket-grouped order; LDS running counters only.
// pairs[pos] = (dst&255)<<24 | src   (src < 2^17 fits low 24 bits)
__global__ __launch_bounds__(256) void k_scat(const int* __restrict__ src,
                                              const int* __restrict__ dst,
                                              const unsigned* __restrict__ H,
                                              unsigned* __restrict__ pairs) {
    __shared__ unsigned base[D1];
    __shared__ unsigned run[D1];
    int b = blockIdx.x, t = threadIdx.x;
    for (int d = t; d < D1; d += 256) { base[d] = H[d * NB + b]; run[d] = 0; }
    __syncthreads();
    int beg = b * CE, end = beg + CE;
    for (int i = beg + t; i < end; i += 256) {
        unsigned dv = (unsigned)dst[i];
        unsigned d = dv >> 8;
        unsigned r = atomicAdd(&run[d], 1u);
        pairs[base[d] + r] = ((dv & 255u) << 24) | (unsigned)src[i];
    }
}

// per-bucket counting sort: emits rowptr, dinv, and csr (= src) for its 256 nodes.
// All scattered writes land in the bucket's own ~16KB window (L2-local).
__global__ __launch_bounds__(256) void k_bucket(const unsigned* __restrict__ H,
                                                const unsigned* __restrict__ pairs,
                                                int* __restrict__ rowptr,
                                                float* __restrict__ dinv,
                                                int* __restrict__ csr) {
    __shared__ unsigned h[256], sc[256], run[256];
    int b = blockIdx.x, t = threadIdx.x;
    unsigned S = H[b * NB];
    unsigned Send = (b + 1 < D1) ? H[(b + 1) * NB] : NE;
    h[t] = 0; run[t] = 0;
    __syncthreads();
    for (unsigned i = S + t; i < Send; i += 256)
        atomicAdd(&h[pairs[i] >> 24], 1u);
    __syncthreads();
    unsigned v = h[t];
    sc[t] = v;
    __syncthreads();
    for (int off = 1; off < 256; off <<= 1) {
        unsigned u = (t >= off) ? sc[t - off] : 0;
        __syncthreads();
        sc[t] += u;
        __syncthreads();
    }
    unsigned ex = sc[t] - v;               // exclusive
    int node = (b << 8) + t;
    if (node < NN) {
        rowptr[node] = (int)(S + ex);
        dinv[node] = rsqrtf((float)v + 1.0f);   // +1 = self-loop
    }
    if (b == 0 && t == 0) rowptr[NN] = NE;
    sc[t] = ex;                            // own slot only, then sync
    __syncthreads();
    for (unsigned i = S + t; i < Send; i += 256) {
        unsigned p = pairs[i];
        unsigned k = p >> 24;
        unsigned r = atomicAdd(&run[k], 1u);
        csr[S + sc[k] + r] = (int)(p & 0xFFFFFFu);
    }
}

// ---------------- layer-1 GEMM: g1 = fp16( dinv .* (x @ W1) ) ----------------

__global__ __launch_bounds__(256, 4) void k_gemm1(const float* __restrict__ A,
                                                  const float* __restrict__ W,
                                                  const float* __restrict__ dinv,
                                                  __half* __restrict__ out, int n) {
    __shared__ float sX[32 * SXS];
    __shared__ float sW[64 * 64];
    int row0 = blockIdx.x * 32;
    for (int i = threadIdx.x; i < 16 * 64; i += 256)
        ((float4*)sW)[i] = ((const float4*)W)[i];
    for (int i = threadIdx.x; i < 32 * 16; i += 256) {
        int r = i >> 4, c4 = i & 15;
        int row = row0 + r;
        float4 v = (row < n) ? ((const float4*)(A + ((size_t)row << 6)))[c4]
                             : make_float4(0.f, 0.f, 0.f, 0.f);
        *(float4*)&sX[r * SXS + (c4 << 2)] = v;
    }
    __syncthreads();

    int ci = (threadIdx.x & 15) * 4;
    int r0 = (threadIdx.x >> 4) * 2;
    float acc[2][4] = {};
#pragma unroll 16
    for (int k = 0; k < 64; ++k) {
        float a0 = sX[r0 * SXS + k];
        float a1 = sX[(r0 + 1) * SXS + k];
        float4 w = *(const float4*)&sW[(k << 6) + ci];
        acc[0][0] += a0 * w.x; acc[0][1] += a0 * w.y;
        acc[0][2] += a0 * w.z; acc[0][3] += a0 * w.w;
        acc[1][0] += a1 * w.x; acc[1][1] += a1 * w.y;
        acc[1][2] += a1 * w.z; acc[1][3] += a1 * w.w;
    }
#pragma unroll
    for (int rr = 0; rr < 2; ++rr) {
        int row = row0 + r0 + rr;
        if (row < n) {
            float di = dinv[row];
            union { uint2 u; __half2 h[2]; } P;
            P.h[0] = __float22half2_rn(make_float2(acc[rr][0] * di, acc[rr][1] * di));
            P.h[1] = __float22half2_rn(make_float2(acc[rr][2] * di, acc[rr][3] * di));
            *(uint2*)(out + ((size_t)row << 6) + ci) = P.u;
        }
    }
}

// ---------------- aggregate: 32 nodes/block, 8-lane group per node ----------------
// t[d] = sum_{s in N(d)} g[s] + g[d]             (g = dinv .* h)
// MODE 1: gout = fp16( relu(dinv*t + bias) * dinv )           [zero LDS ops]
// MODE 2: h = relu(dinv*t + bias); gout = fp16( (h @ Wn) * dinv )
// MODE 3: fout = (dinv*t) @ Wn + bias2            (M = 40, fp32 out)

#define ACC8(r) { \
    const __half2* hh_ = (const __half2*)&(r); \
    float2 f_; \
    f_ = __half22float2(hh_[0]); a[0].x += f_.x; a[0].y += f_.y; \
    f_ = __half22float2(hh_[1]); a[1].x += f_.x; a[1].y += f_.y; \
    f_ = __half22float2(hh_[2]); a[2].x += f_.x; a[2].y += f_.y; \
    f_ = __half22float2(hh_[3]); a[3].x += f_.x; a[3].y += f_.y; }

template <int MODE>
__global__ __launch_bounds__(256) void k_agg(const int* __restrict__ rowptr,
                                             const int* __restrict__ csr,
                                             const __half* __restrict__ g,
                                             const float* __restrict__ dinv,
                                             const float* __restrict__ bias,
                                             const float* __restrict__ Wn,
                                             const float* __restrict__ bias2,
                                             void* __restrict__ outv, int n) {
    constexpr int M = (MODE == 3) ? 40 : 64;
    __shared__ float sW[(MODE >= 2) ? 64 * M : 1];
    __shared__ float sT[(MODE >= 2) ? 32 * ST : 1];
    int tid = threadIdx.x;
    if (MODE >= 2) {
        for (int i = tid; i < 16 * M; i += 256)
            ((float4*)sW)[i] = ((const float4*)Wn)[i];
    }
    int n0 = blockIdx.x << 5;
    int lane = tid & 63, wid = tid >> 6;
    int ng = lane >> 3, fl = lane & 7;
    int nl = (wid << 3) + ng;              // block-local node 0..31
    int node = n0 + nl;
    bool valid = node < n;
    const uint4* g4 = (const uint4*)g;     // one row = 8 uint4 (64 halves)

    int beg = 0, end = 0;
    if (valid) { beg = rowptr[node]; end = rowptr[node + 1]; }
    float2 a[4] = {};
    int j = beg;
    for (; j + 4 <= end; j += 4) {         // 4 independent gathers in flight
        int s0 = csr[j], s1 = csr[j + 1], s2 = csr[j + 2], s3 = csr[j + 3];
        uint4 r0 = g4[((size_t)s0 << 3) + fl];
        uint4 r1 = g4[((size_t)s1 << 3) + fl];
        uint4 r2 = g4[((size_t)s2 << 3) + fl];
        uint4 r3 = g4[((size_t)s3 << 3) + fl];
        ACC8(r0); ACC8(r1); ACC8(r2); ACC8(r3);
    }
    for (; j < end; ++j) {
        int s = csr[j];
        uint4 r = g4[((size_t)s << 3) + fl];
        ACC8(r);
    }
    if (valid) {                           // self-loop
        uint4 r = g4[((size_t)node << 3) + fl];
        ACC8(r);
    }
    float di = valid ? dinv[node] : 0.f;
    float t[8] = { a[0].x, a[0].y, a[1].x, a[1].y, a[2].x, a[2].y, a[3].x, a[3].y };

    if (MODE == 1) {
        if (valid) {
            float4 b0 = *(const float4*)(bias + (fl << 3));
            float4 b1 = *(const float4*)(bias + (fl << 3) + 4);
            float bv[8] = { b0.x, b0.y, b0.z, b0.w, b1.x, b1.y, b1.z, b1.w };
            union { uint4 u; __half2 h[4]; } P;
#pragma unroll
            for (int k = 0; k < 4; ++k) {
                float o0 = fmaxf(t[2 * k]     * di + bv[2 * k],     0.f) * di;
                float o1 = fmaxf(t[2 * k + 1] * di + bv[2 * k + 1], 0.f) * di;
                P.h[k] = __float22half2_rn(make_float2(o0, o1));
            }
            ((uint4*)outv)[((size_t)node << 3) + fl] = P.u;
        }
        return;
    }

    // MODE 2/3: stash transformed row slice into sT
    {
        float4 b0 = make_float4(0.f, 0.f, 0.f, 0.f), b1 = b0;
        if (MODE == 2) {
            b0 = *(const float4*)(bias + (fl << 3));
            b1 = *(const float4*)(bias + (fl << 3) + 4);
        }
        float bv[8] = { b0.x, b0.y, b0.z, b0.w, b1.x, b1.y, b1.z, b1.w };
        float* row = &sT[nl * ST + (fl << 3)];
#pragma unroll
        for (int k = 0; k < 8; ++k) {
            float v = t[k] * di;
            if (MODE == 2) v = fmaxf(v + bv[k], 0.f);
            row[k] = v;
        }
    }
    __syncthreads();

    // matvec over the 32 staged rows: thread = 2 nodes x 4 cols
    int rg = tid >> 4;                 // 0..15 -> nodes 2rg, 2rg+1
    int cq = (tid & 15) << 2;          // col quad
    if (cq < M) {
        float s0[4] = {}, s1[4] = {};
#pragma unroll 8
        for (int k = 0; k < 64; ++k) {
            float4 w = *(const float4*)&sW[k * M + cq];
            float a0 = sT[(rg * 2) * ST + k];
            float a1 = sT[(rg * 2 + 1) * ST + k];
            s0[0] += a0 * w.x; s0[1] += a0 * w.y; s0[2] += a0 * w.z; s0[3] += a0 * w.w;
            s1[0] += a1 * w.x; s1[1] += a1 * w.y; s1[2] += a1 * w.z; s1[3] += a1 * w.w;
        }
#pragma unroll
        for (int r = 0; r < 2; ++r) {
            float* s = (r == 0) ? s0 : s1;
            int node2 = n0 + rg * 2 + r;
            if (node2 < n) {
                if (MODE == 2) {
                    float d2 = dinv[node2];
                    union { uint2 u; __half2 h[2]; } P;
                    P.h[0] = __float22half2_rn(make_float2(s[0] * d2, s[1] * d2));
                    P.h[1] = __float22half2_rn(make_float2(s[2] * d2, s[3] * d2));
                    *(uint2*)((__half*)outv + ((size_t)node2 << 6) + cq) = P.u;
                } else {
                    float4 o = make_float4(s[0] + bias2[cq],     s[1] + bias2[cq + 1],
                                           s[2] + bias2[cq + 2], s[3] + bias2[cq + 3]);
                    *(float4*)((float*)outv + (size_t)node2 * 40 + cq) = o;
                }
            }
        }
    }
}

extern "C" void kernel_launch(void* const* d_in, const int* in_sizes, int n_in,
                              void* d_out, int out_size, void* d_ws, size_t ws_size,
                              hipStream_t stream) {
    const float* x  = (const float*)d_in[0];
    const int*   ei = (const int*)d_in[1];   // [2 x E]: row0 = src, row1 = dst
    const float* W1 = (const float*)d_in[2];
    const float* b1 = (const float*)d_in[3];
    const float* W2 = (const float*)d_in[4];
    const float* b2 = (const float*)d_in[5];
    const float* W3 = (const float*)d_in[6];
    const float* b3 = (const float*)d_in[7];
    float* out = (float*)d_out;

    const int* src = ei;
    const int* dst = ei + NE;

    // workspace: H[L1] | bsum[512] | rowptr[NPAD] | dinv[NPAD] | pairs[NE] |
    //            csr[NE] | gA half[N*64] | gB half[N*64]
    unsigned* H      = (unsigned*)d_ws;
    unsigned* bsum   = H + L1;
    int*      rowptr = (int*)(bsum + 512);
    float*    dinv   = (float*)(rowptr + NPAD);
    unsigned* pairs  = (unsigned*)(dinv + NPAD);
    int*      csr    = (int*)(pairs + NE);
    __half*   gA     = (__half*)(csr + NE);
    __half*   gB     = gA + (size_t)NN * 64;

    const int B = 256;
    const int gG = (NN + 31) / 32;
    const int gAgg = (NN + 31) / 32;      // 32 nodes per block
    const int nScan = (L1 + 255) / 256;   // 391

    // ---- CSR build (bucket sort, no scattered global atomics) ----
    k_hist<<<NB, B, 0, stream>>>(dst, H);
    k_scanA<<<nScan, B, 0, stream>>>(H, bsum, L1);
    k_scanB<<<1, 512, 0, stream>>>(bsum, nScan);
    k_scanC<<<nScan, B, 0, stream>>>(H, bsum, L1);
    k_scat<<<NB, B, 0, stream>>>(src, dst, H, pairs);
    k_bucket<<<D1, B, 0, stream>>>(H, pairs, rowptr, dinv, csr);

    // ---- layer 1 GEMM (scaled fp16 out): gA = fp16(dinv .* (x @ W1)) ----
    k_gemm1<<<gG, B, 0, stream>>>(x, W1, dinv, gA, NN);
    // ---- AGG1 fused: gB = fp16(dinv .* (relu(dinv*t + b1) @ W2)) ----
    k_agg<2><<<gAgg, B, 0, stream>>>(rowptr, csr, gA, dinv, b1, W2, nullptr, gB, NN);
    // ---- AGG2: gA = fp16(dinv .* relu(dinv*t + b2)) ----
    k_agg<1><<<gAgg, B, 0, stream>>>(rowptr, csr, gB, dinv, b2, nullptr, nullptr, gA, NN);
    // ---- AGG3 fused: out = (dinv*t) @ W3 + b3 ----
    k_agg<3><<<gAgg, B, 0, stream>>>(rowptr, csr, gA, dinv, nullptr, W3, b3, out, NN);
}